// Round 1
// baseline (7783.098 us; speedup 1.0000x reference)
//
#include <hip/hip_runtime.h>
#include <hip/hip_bf16.h>

#define N_NODES 100000
#define N_EDGES 3200000
#define IN_F 512
#define HID 64
#define OUT_F 64
#define K_HOPS 10

// ---------------------------------------------------------------------------
// Detect edge_index storage: int64 (high 32-bit words all zero) vs int32.
// Checks the first 1024 odd 32-bit words; any nonzero => int32 layout.
__global__ void detect_i32_kernel(const unsigned int* ei_words, int* flag_is32) {
    int i = blockIdx.x * blockDim.x + threadIdx.x;  // 0..1023
    unsigned int w = ei_words[2 * i + 1];
    if (w != 0u) atomicOr(flag_is32, 1);
}

// Convert edges to int32 src/dst and count degrees.
__global__ void edges_deg_kernel(const void* ei_raw, const int* flag_is32,
                                 int* src32, int* dst32, int* deg_out, int* deg_in) {
    int e = blockIdx.x * blockDim.x + threadIdx.x;
    if (e >= N_EDGES) return;
    int s, d;
    if (*flag_is32) {
        const int* ei = (const int*)ei_raw;
        s = ei[e];
        d = ei[N_EDGES + e];
    } else {
        const long long* ei = (const long long*)ei_raw;
        s = (int)ei[e];
        d = (int)ei[N_EDGES + e];
    }
    src32[e] = s;
    dst32[e] = d;
    atomicAdd(&deg_out[s], 1);
    atomicAdd(&deg_in[d], 1);
}

__global__ void dinv_kernel(const int* deg_out, const int* deg_in,
                            float* dinv_out, float* dinv_in) {
    int i = blockIdx.x * blockDim.x + threadIdx.x;
    if (i >= N_NODES) return;
    int a = deg_out[i];
    int b = deg_in[i];
    dinv_out[i] = (a > 0) ? rsqrtf((float)a) : 0.0f;
    dinv_in[i]  = (b > 0) ? rsqrtf((float)b) : 0.0f;
}

__global__ void norm_kernel(const int* src32, const int* dst32,
                            const float* dinv_out, const float* dinv_in, float* norm) {
    int e = blockIdx.x * blockDim.x + threadIdx.x;
    if (e >= N_EDGES) return;
    norm[e] = dinv_out[src32[e]] * dinv_in[dst32[e]];
}

// ---------------------------------------------------------------------------
// MLP: h = relu(relu(x@W1)@W2).  One wave handles NB=8 nodes (register
// blocking so each W1 column-load is reused 8x; W1 stays hot in L2).
#define MLP_NB 8
__global__ void __launch_bounds__(256) mlp_kernel(const float* __restrict__ x,
                                                  const float* __restrict__ W1,
                                                  const float* __restrict__ W2,
                                                  float* __restrict__ h) {
    int lane = threadIdx.x & 63;
    int wave_in_blk = __builtin_amdgcn_readfirstlane(threadIdx.x >> 6);
    int wave_id = blockIdx.x * 4 + wave_in_blk;        // global wave index
    int node0 = wave_id * MLP_NB;
    if (node0 >= N_NODES) return;

    float acc[MLP_NB];
#pragma unroll
    for (int n = 0; n < MLP_NB; ++n) acc[n] = 0.0f;

    const float* xr = x + (size_t)node0 * IN_F;
#pragma unroll 4
    for (int k = 0; k < IN_F; ++k) {
        float w = W1[k * HID + lane];                  // coalesced, L2-hot
#pragma unroll
        for (int n = 0; n < MLP_NB; ++n) {
            acc[n] = fmaf(xr[(size_t)n * IN_F + k], w, acc[n]);  // broadcast load
        }
    }
#pragma unroll
    for (int n = 0; n < MLP_NB; ++n) acc[n] = fmaxf(acc[n], 0.0f);

    // layer 2: h1[n][k] lives in lane k's acc[n]
    float acc2[MLP_NB];
#pragma unroll
    for (int n = 0; n < MLP_NB; ++n) acc2[n] = 0.0f;
    for (int k = 0; k < HID; ++k) {
        float w = W2[k * OUT_F + lane];
#pragma unroll
        for (int n = 0; n < MLP_NB; ++n) {
            float hk = __shfl(acc[n], k, 64);
            acc2[n] = fmaf(hk, w, acc2[n]);
        }
    }
#pragma unroll
    for (int n = 0; n < MLP_NB; ++n) {
        h[(size_t)(node0 + n) * OUT_F + lane] = fmaxf(acc2[n], 0.0f);
    }
}

// ---------------------------------------------------------------------------
// One propagation hop, edge-parallel: 64 lanes per edge, atomic scatter-add.
__global__ void __launch_bounds__(256) hop_kernel(const float* __restrict__ feat,
                                                  const int* __restrict__ src,
                                                  const int* __restrict__ dst,
                                                  const float* __restrict__ norm,
                                                  float* __restrict__ fnext) {
    int gid = blockIdx.x * blockDim.x + threadIdx.x;
    int e = gid >> 6;
    int j = gid & 63;
    if (e >= N_EDGES) return;
    float v = feat[(size_t)src[e] * OUT_F + j] * norm[e];
    atomicAdd(&fnext[(size_t)dst[e] * OUT_F + j], v);
}

// ---------------------------------------------------------------------------
// out (+)= sigmoid(feat . s) * feat   — one wave per node, shuffle-reduce dot.
__global__ void __launch_bounds__(256) combine_kernel(const float* __restrict__ feat,
                                                      const float* __restrict__ sv,
                                                      float* __restrict__ out,
                                                      int first) {
    int lane = threadIdx.x & 63;
    int wave_in_blk = __builtin_amdgcn_readfirstlane(threadIdx.x >> 6);
    int node = blockIdx.x * 4 + wave_in_blk;
    if (node >= N_NODES) return;
    float v = feat[(size_t)node * OUT_F + lane];
    float p = v * sv[lane];
#pragma unroll
    for (int off = 32; off >= 1; off >>= 1) p += __shfl_xor(p, off, 64);
    float score = 1.0f / (1.0f + expf(-p));
    float contrib = score * v;
    size_t idx = (size_t)node * OUT_F + lane;
    if (first) out[idx] = contrib;
    else       out[idx] += contrib;
}

// ---------------------------------------------------------------------------
extern "C" void kernel_launch(void* const* d_in, const int* in_sizes, int n_in,
                              void* d_out, int out_size, void* d_ws, size_t ws_size,
                              hipStream_t stream) {
    const float* x  = (const float*)d_in[0];
    const void*  ei = d_in[1];
    const float* W1 = (const float*)d_in[2];
    const float* W2 = (const float*)d_in[3];
    const float* sv = (const float*)d_in[4];
    float* out = (float*)d_out;

    char* p = (char*)d_ws;
    auto alloc = [&](size_t bytes) -> char* {
        char* r = p;
        p += (bytes + 255) & ~(size_t)255;
        return r;
    };
    float* fA       = (float*)alloc(sizeof(float) * N_NODES * OUT_F);
    float* fB       = (float*)alloc(sizeof(float) * N_NODES * OUT_F);
    int*   src32    = (int*)alloc(sizeof(int) * N_EDGES);
    int*   dst32    = (int*)alloc(sizeof(int) * N_EDGES);
    float* norm     = (float*)alloc(sizeof(float) * N_EDGES);
    int*   deg_out  = (int*)alloc(sizeof(int) * N_NODES);
    int*   deg_in   = (int*)alloc(sizeof(int) * N_NODES);
    float* dinv_out = (float*)alloc(sizeof(float) * N_NODES);
    float* dinv_in  = (float*)alloc(sizeof(float) * N_NODES);
    int*   flag     = (int*)alloc(256);

    hipMemsetAsync(deg_out, 0, sizeof(int) * N_NODES, stream);
    hipMemsetAsync(deg_in,  0, sizeof(int) * N_NODES, stream);
    hipMemsetAsync(flag,    0, sizeof(int), stream);

    detect_i32_kernel<<<4, 256, 0, stream>>>((const unsigned int*)ei, flag);
    edges_deg_kernel<<<(N_EDGES + 255) / 256, 256, 0, stream>>>(ei, flag, src32, dst32,
                                                                deg_out, deg_in);
    dinv_kernel<<<(N_NODES + 255) / 256, 256, 0, stream>>>(deg_out, deg_in,
                                                           dinv_out, dinv_in);
    norm_kernel<<<(N_EDGES + 255) / 256, 256, 0, stream>>>(src32, dst32,
                                                           dinv_out, dinv_in, norm);

    // waves = N/8, threads = waves*64, blocks = threads/256
    int mlp_blocks = (N_NODES / MLP_NB * 64 + 255) / 256;   // 3125
    mlp_kernel<<<mlp_blocks, 256, 0, stream>>>(x, W1, W2, fA);

    int node_blocks = (N_NODES * 64 + 255) / 256;           // 25000
    combine_kernel<<<node_blocks, 256, 0, stream>>>(fA, sv, out, 1);

    int hop_blocks = (int)(((size_t)N_EDGES * 64 + 255) / 256);  // 800000
    float* cur = fA;
    float* nxt = fB;
    for (int hop = 0; hop < K_HOPS; ++hop) {
        hipMemsetAsync(nxt, 0, sizeof(float) * N_NODES * OUT_F, stream);
        hop_kernel<<<hop_blocks, 256, 0, stream>>>(cur, src32, dst32, norm, nxt);
        combine_kernel<<<node_blocks, 256, 0, stream>>>(nxt, sv, out, 0);
        float* t = cur; cur = nxt; nxt = t;
    }
}

// Round 2
// 2050.795 us; speedup vs baseline: 3.7952x; 3.7952x over previous
//
#include <hip/hip_runtime.h>
#include <hip/hip_bf16.h>

#define N_NODES 100000
#define N_EDGES 3200000
#define IN_F 512
#define HID 64
#define OUT_F 64
#define K_HOPS 10
#define N_SCAN_BLOCKS ((N_NODES + 255) / 256)   // 391

// ---------------------------------------------------------------------------
// Detect edge_index storage: int64 (high 32-bit words all zero) vs int32.
__global__ void detect_i32_kernel(const unsigned int* ei_words, int* flag_is32) {
    int i = blockIdx.x * blockDim.x + threadIdx.x;  // 0..1023
    unsigned int w = ei_words[2 * i + 1];
    if (w != 0u) atomicOr(flag_is32, 1);
}

// Convert edges to int32 src/dst and count degrees.
__global__ void edges_deg_kernel(const void* ei_raw, const int* flag_is32,
                                 int* src32, int* dst32, int* deg_out, int* deg_in) {
    int e = blockIdx.x * blockDim.x + threadIdx.x;
    if (e >= N_EDGES) return;
    int s, d;
    if (*flag_is32) {
        const int* ei = (const int*)ei_raw;
        s = ei[e];
        d = ei[N_EDGES + e];
    } else {
        const long long* ei = (const long long*)ei_raw;
        s = (int)ei[e];
        d = (int)ei[N_EDGES + e];
    }
    src32[e] = s;
    dst32[e] = d;
    atomicAdd(&deg_out[s], 1);
    atomicAdd(&deg_in[d], 1);
}

__global__ void dinv_kernel(const int* deg_out, const int* deg_in,
                            float* dinv_out, float* dinv_in) {
    int i = blockIdx.x * blockDim.x + threadIdx.x;
    if (i >= N_NODES) return;
    int a = deg_out[i];
    int b = deg_in[i];
    dinv_out[i] = (a > 0) ? rsqrtf((float)a) : 0.0f;
    dinv_in[i]  = (b > 0) ? rsqrtf((float)b) : 0.0f;
}

// --------------------------- CSR build (counting sort by dst) ---------------
__global__ void block_sum_kernel(const int* __restrict__ deg, int* __restrict__ partial) {
    __shared__ int s[256];
    int t = threadIdx.x;
    int i = blockIdx.x * 256 + t;
    s[t] = (i < N_NODES) ? deg[i] : 0;
    __syncthreads();
    for (int off = 128; off >= 1; off >>= 1) {
        if (t < off) s[t] += s[t + off];
        __syncthreads();
    }
    if (t == 0) partial[blockIdx.x] = s[0];
}

__global__ void scan_partial_kernel(int* partial, int* row_start) {
    if (threadIdx.x == 0 && blockIdx.x == 0) {
        int acc = 0;
        for (int b = 0; b < N_SCAN_BLOCKS; ++b) {
            int v = partial[b];
            partial[b] = acc;
            acc += v;
        }
        row_start[N_NODES] = acc;   // == N_EDGES
    }
}

__global__ void row_start_kernel(const int* __restrict__ deg, const int* __restrict__ partial,
                                 int* __restrict__ row_start, int* __restrict__ cursor) {
    __shared__ int s[256];
    int t = threadIdx.x;
    int i = blockIdx.x * 256 + t;
    int v = (i < N_NODES) ? deg[i] : 0;
    s[t] = v;
    __syncthreads();
    for (int off = 1; off < 256; off <<= 1) {   // Hillis-Steele inclusive scan
        int add = (t >= off) ? s[t - off] : 0;
        __syncthreads();
        s[t] += add;
        __syncthreads();
    }
    if (i < N_NODES) {
        int excl = s[t] - v + partial[blockIdx.x];
        row_start[i] = excl;
        cursor[i] = excl;
    }
}

__global__ void scatter_kernel(const int* __restrict__ src32, const int* __restrict__ dst32,
                               const float* __restrict__ dinv_out, const float* __restrict__ dinv_in,
                               int* __restrict__ cursor,
                               int* __restrict__ csr_src, float* __restrict__ csr_norm) {
    int e = blockIdx.x * blockDim.x + threadIdx.x;
    if (e >= N_EDGES) return;
    int s = src32[e], d = dst32[e];
    float nrm = dinv_out[s] * dinv_in[d];
    int pos = atomicAdd(&cursor[d], 1);
    csr_src[pos] = s;
    csr_norm[pos] = nrm;
}

// ---------------------------------------------------------------------------
// MLP: h = relu(relu(x@W1)@W2).  One wave handles NB=8 nodes.
#define MLP_NB 8
__global__ void __launch_bounds__(256) mlp_kernel(const float* __restrict__ x,
                                                  const float* __restrict__ W1,
                                                  const float* __restrict__ W2,
                                                  float* __restrict__ h) {
    int lane = threadIdx.x & 63;
    int wave_in_blk = __builtin_amdgcn_readfirstlane(threadIdx.x >> 6);
    int wave_id = blockIdx.x * 4 + wave_in_blk;
    int node0 = wave_id * MLP_NB;
    if (node0 >= N_NODES) return;

    float acc[MLP_NB];
#pragma unroll
    for (int n = 0; n < MLP_NB; ++n) acc[n] = 0.0f;

    const float* xr = x + (size_t)node0 * IN_F;
#pragma unroll 4
    for (int k = 0; k < IN_F; ++k) {
        float w = W1[k * HID + lane];
#pragma unroll
        for (int n = 0; n < MLP_NB; ++n) {
            acc[n] = fmaf(xr[(size_t)n * IN_F + k], w, acc[n]);
        }
    }
#pragma unroll
    for (int n = 0; n < MLP_NB; ++n) acc[n] = fmaxf(acc[n], 0.0f);

    float acc2[MLP_NB];
#pragma unroll
    for (int n = 0; n < MLP_NB; ++n) acc2[n] = 0.0f;
    for (int k = 0; k < HID; ++k) {
        float w = W2[k * OUT_F + lane];
#pragma unroll
        for (int n = 0; n < MLP_NB; ++n) {
            float hk = __shfl(acc[n], k, 64);
            acc2[n] = fmaf(hk, w, acc2[n]);
        }
    }
#pragma unroll
    for (int n = 0; n < MLP_NB; ++n) {
        h[(size_t)(node0 + n) * OUT_F + lane] = fmaxf(acc2[n], 0.0f);
    }
}

// ---------------------------------------------------------------------------
// out (+)= sigmoid(feat . s) * feat   — initial combine for hop 0 (h itself).
__global__ void __launch_bounds__(256) combine_kernel(const float* __restrict__ feat,
                                                      const float* __restrict__ sv,
                                                      float* __restrict__ out) {
    int lane = threadIdx.x & 63;
    int wave_in_blk = __builtin_amdgcn_readfirstlane(threadIdx.x >> 6);
    int node = blockIdx.x * 4 + wave_in_blk;
    if (node >= N_NODES) return;
    float v = feat[(size_t)node * OUT_F + lane];
    float p = v * sv[lane];
#pragma unroll
    for (int off = 32; off >= 1; off >>= 1) p += __shfl_xor(p, off, 64);
    float score = 1.0f / (1.0f + expf(-p));
    out[(size_t)node * OUT_F + lane] = score * v;
}

// ---------------------------------------------------------------------------
// One propagation hop + fused gate-combine.  One wave per dst node:
// 4 edges in flight (16 lanes x float4 each), register accumulation,
// no atomics, no memset (full row written unconditionally).
__global__ void __launch_bounds__(256) hop_combine_kernel(
        const float* __restrict__ feat,
        const int* __restrict__ row_start,
        const int* __restrict__ csr_src,
        const float* __restrict__ csr_norm,
        const float* __restrict__ sv,
        float* __restrict__ fnext,
        float* __restrict__ out) {
    int lane = threadIdx.x & 63;
    int node = blockIdx.x * 4 + (threadIdx.x >> 6);
    if (node >= N_NODES) return;
    int beg = row_start[node];
    int end = row_start[node + 1];
    int slot = lane >> 4;    // 0..3: which edge of the group of 4
    int f4   = lane & 15;    // which float4 of the 64-float row

    const float4* feat4 = (const float4*)feat;
    float4 acc = make_float4(0.f, 0.f, 0.f, 0.f);
    for (int i = beg + slot; i < end; i += 4) {
        int s = csr_src[i];          // 16 lanes broadcast-load same dword
        float nrm = csr_norm[i];
        float4 v = feat4[(size_t)s * 16 + f4];
        acc.x = fmaf(v.x, nrm, acc.x);
        acc.y = fmaf(v.y, nrm, acc.y);
        acc.z = fmaf(v.z, nrm, acc.z);
        acc.w = fmaf(v.w, nrm, acc.w);
    }
    // reduce the 4 edge-slots (lanes differing in bits 4..5)
#pragma unroll
    for (int off = 16; off <= 32; off <<= 1) {
        acc.x += __shfl_xor(acc.x, off, 64);
        acc.y += __shfl_xor(acc.y, off, 64);
        acc.z += __shfl_xor(acc.z, off, 64);
        acc.w += __shfl_xor(acc.w, off, 64);
    }
    // gate: p = acc . s  (reduce over the 16 f4-lanes; value replicated per slot)
    float4 sv4 = ((const float4*)sv)[f4];
    float p = acc.x * sv4.x + acc.y * sv4.y + acc.z * sv4.z + acc.w * sv4.w;
#pragma unroll
    for (int off = 1; off <= 8; off <<= 1) p += __shfl_xor(p, off, 64);
    float score = 1.0f / (1.0f + expf(-p));

    if (slot == 0) {   // lanes 0..15 write the full 256B row
        size_t idx = (size_t)node * 16 + f4;
        ((float4*)fnext)[idx] = acc;
        float4 o = ((const float4*)out)[idx];
        o.x = fmaf(score, acc.x, o.x);
        o.y = fmaf(score, acc.y, o.y);
        o.z = fmaf(score, acc.z, o.z);
        o.w = fmaf(score, acc.w, o.w);
        ((float4*)out)[idx] = o;
    }
}

// ---------------------------------------------------------------------------
extern "C" void kernel_launch(void* const* d_in, const int* in_sizes, int n_in,
                              void* d_out, int out_size, void* d_ws, size_t ws_size,
                              hipStream_t stream) {
    const float* x  = (const float*)d_in[0];
    const void*  ei = d_in[1];
    const float* W1 = (const float*)d_in[2];
    const float* W2 = (const float*)d_in[3];
    const float* sv = (const float*)d_in[4];
    float* out = (float*)d_out;

    char* p = (char*)d_ws;
    auto alloc = [&](size_t bytes) -> char* {
        char* r = p;
        p += (bytes + 255) & ~(size_t)255;
        return r;
    };
    float* fA        = (float*)alloc(sizeof(float) * N_NODES * OUT_F);
    float* fB        = (float*)alloc(sizeof(float) * N_NODES * OUT_F);
    int*   src32     = (int*)alloc(sizeof(int) * N_EDGES);
    int*   dst32     = (int*)alloc(sizeof(int) * N_EDGES);
    int*   csr_src   = (int*)alloc(sizeof(int) * N_EDGES);
    float* csr_norm  = (float*)alloc(sizeof(float) * N_EDGES);
    int*   deg_out   = (int*)alloc(sizeof(int) * N_NODES);
    int*   deg_in    = (int*)alloc(sizeof(int) * N_NODES);
    float* dinv_out  = (float*)alloc(sizeof(float) * N_NODES);
    float* dinv_in   = (float*)alloc(sizeof(float) * N_NODES);
    int*   row_start = (int*)alloc(sizeof(int) * (N_NODES + 1));
    int*   cursor    = (int*)alloc(sizeof(int) * N_NODES);
    int*   partial   = (int*)alloc(sizeof(int) * N_SCAN_BLOCKS);
    int*   flag      = (int*)alloc(256);

    hipMemsetAsync(deg_out, 0, sizeof(int) * N_NODES, stream);
    hipMemsetAsync(deg_in,  0, sizeof(int) * N_NODES, stream);
    hipMemsetAsync(flag,    0, sizeof(int), stream);

    detect_i32_kernel<<<4, 256, 0, stream>>>((const unsigned int*)ei, flag);
    edges_deg_kernel<<<(N_EDGES + 255) / 256, 256, 0, stream>>>(ei, flag, src32, dst32,
                                                                deg_out, deg_in);
    dinv_kernel<<<(N_NODES + 255) / 256, 256, 0, stream>>>(deg_out, deg_in,
                                                           dinv_out, dinv_in);
    // CSR build (counting sort by dst)
    block_sum_kernel<<<N_SCAN_BLOCKS, 256, 0, stream>>>(deg_in, partial);
    scan_partial_kernel<<<1, 64, 0, stream>>>(partial, row_start);
    row_start_kernel<<<N_SCAN_BLOCKS, 256, 0, stream>>>(deg_in, partial, row_start, cursor);
    scatter_kernel<<<(N_EDGES + 255) / 256, 256, 0, stream>>>(src32, dst32, dinv_out, dinv_in,
                                                              cursor, csr_src, csr_norm);

    int mlp_blocks = (N_NODES / MLP_NB * 64 + 255) / 256;   // 3125
    mlp_kernel<<<mlp_blocks, 256, 0, stream>>>(x, W1, W2, fA);

    int node_blocks = (N_NODES + 3) / 4;                    // 4 nodes (waves) per block
    combine_kernel<<<node_blocks, 256, 0, stream>>>(fA, sv, out);

    float* cur = fA;
    float* nxt = fB;
    for (int hop = 0; hop < K_HOPS; ++hop) {
        hop_combine_kernel<<<node_blocks, 256, 0, stream>>>(cur, row_start, csr_src,
                                                            csr_norm, sv, nxt, out);
        combine_kernel; // (fused above)
        float* t = cur; cur = nxt; nxt = t;
    }
}

// Round 3
// 1263.991 us; speedup vs baseline: 6.1576x; 1.6225x over previous
//
#include <hip/hip_runtime.h>
#include <hip/hip_bf16.h>

#define N_NODES 100000
#define N_EDGES 3200000
#define IN_F 512
#define HID 64
#define OUT_F 64
#define K_HOPS 10
#define N_SCAN_BLOCKS ((N_NODES + 255) / 256)   // 391

static __device__ __forceinline__ unsigned short f2bf(float f) {
    unsigned int u = __float_as_uint(f);
    u += 0x7FFFu + ((u >> 16) & 1u);            // round-to-nearest-even
    return (unsigned short)(u >> 16);
}
static __device__ __forceinline__ float bf2f(unsigned short s) {
    return __uint_as_float(((unsigned int)s) << 16);
}

// ---------------------------------------------------------------------------
// Detect edge_index storage: int64 (high 32-bit words all zero) vs int32.
__global__ void detect_i32_kernel(const unsigned int* ei_words, int* flag_is32) {
    int i = blockIdx.x * blockDim.x + threadIdx.x;  // 0..1023
    unsigned int w = ei_words[2 * i + 1];
    if (w != 0u) atomicOr(flag_is32, 1);
}

__global__ void edges_deg_kernel(const void* ei_raw, const int* flag_is32,
                                 int* src32, int* dst32, int* deg_out, int* deg_in) {
    int e = blockIdx.x * blockDim.x + threadIdx.x;
    if (e >= N_EDGES) return;
    int s, d;
    if (*flag_is32) {
        const int* ei = (const int*)ei_raw;
        s = ei[e];
        d = ei[N_EDGES + e];
    } else {
        const long long* ei = (const long long*)ei_raw;
        s = (int)ei[e];
        d = (int)ei[N_EDGES + e];
    }
    src32[e] = s;
    dst32[e] = d;
    atomicAdd(&deg_out[s], 1);
    atomicAdd(&deg_in[d], 1);
}

__global__ void dinv_kernel(const int* deg_out, const int* deg_in,
                            float* dinv_out, float* dinv_in) {
    int i = blockIdx.x * blockDim.x + threadIdx.x;
    if (i >= N_NODES) return;
    int a = deg_out[i];
    int b = deg_in[i];
    dinv_out[i] = (a > 0) ? rsqrtf((float)a) : 0.0f;
    dinv_in[i]  = (b > 0) ? rsqrtf((float)b) : 0.0f;
}

// --------------------------- CSR build (counting sort by dst) ---------------
__global__ void block_sum_kernel(const int* __restrict__ deg, int* __restrict__ partial) {
    __shared__ int s[256];
    int t = threadIdx.x;
    int i = blockIdx.x * 256 + t;
    s[t] = (i < N_NODES) ? deg[i] : 0;
    __syncthreads();
    for (int off = 128; off >= 1; off >>= 1) {
        if (t < off) s[t] += s[t + off];
        __syncthreads();
    }
    if (t == 0) partial[blockIdx.x] = s[0];
}

__global__ void scan_partial_kernel(int* partial, int* row_start) {
    if (threadIdx.x == 0 && blockIdx.x == 0) {
        int acc = 0;
        for (int b = 0; b < N_SCAN_BLOCKS; ++b) {
            int v = partial[b];
            partial[b] = acc;
            acc += v;
        }
        row_start[N_NODES] = acc;
    }
}

__global__ void row_start_kernel(const int* __restrict__ deg, const int* __restrict__ partial,
                                 int* __restrict__ row_start, int* __restrict__ cursor) {
    __shared__ int s[256];
    int t = threadIdx.x;
    int i = blockIdx.x * 256 + t;
    int v = (i < N_NODES) ? deg[i] : 0;
    s[t] = v;
    __syncthreads();
    for (int off = 1; off < 256; off <<= 1) {
        int add = (t >= off) ? s[t - off] : 0;
        __syncthreads();
        s[t] += add;
        __syncthreads();
    }
    if (i < N_NODES) {
        int excl = s[t] - v + partial[blockIdx.x];
        row_start[i] = excl;
        cursor[i] = excl;
    }
}

__global__ void scatter_kernel(const int* __restrict__ src32, const int* __restrict__ dst32,
                               const float* __restrict__ dinv_out, const float* __restrict__ dinv_in,
                               int* __restrict__ cursor, int2* __restrict__ csr) {
    int e = blockIdx.x * blockDim.x + threadIdx.x;
    if (e >= N_EDGES) return;
    int s = src32[e], d = dst32[e];
    float nrm = dinv_out[s] * dinv_in[d];
    int pos = atomicAdd(&cursor[d], 1);
    csr[pos] = make_int2(s, __float_as_int(nrm));
}

// ---------------------------------------------------------------------------
// Fused 2-layer MLP: h = relu(relu(x@W1)@W2), output bf16.
// Block = 256 threads = 64-node tile; 4x4 register micro-tiles (16x16 thread grid).
// Phase 1 LDS: xs = x-tile transposed [32][68] (pad 68 keeps float4 reads 16B
// aligned and banks spread), ws = W1 tile [32][64].
// Phase 2 LDS (reuses same memory): h1t [64][68] (h1 transposed), ws2 [64][64].
__global__ void __launch_bounds__(256) mlp_kernel(const float* __restrict__ x,
                                                  const float* __restrict__ W1,
                                                  const float* __restrict__ W2,
                                                  unsigned short* __restrict__ h) {
    __shared__ float smem[64 * 68 + 64 * 64];   // 33.8 KB
    float* xs  = smem;                           // [32][68]
    float* ws  = smem + 32 * 68;                 // [32][64]
    float* h1t = smem;                           // [64][68]
    float* ws2 = smem + 64 * 68;                 // [64][64]

    int tid = threadIdx.x;
    int cx = tid & 15;      // output col group (cols 4cx..4cx+3)
    int ry = tid >> 4;      // output row group (rows 4ry..4ry+3)
    int row0 = blockIdx.x * 64;

    int lr = tid >> 2;      // 0..63: x staging row
    int lq = tid & 3;       // 0..3:  x staging quad (8 floats)
    int wr = tid >> 3;      // 0..31: W1 staging row
    int wq = tid & 7;       // 0..7:  W1 staging col8

    float c1[4][4];
#pragma unroll
    for (int i = 0; i < 4; ++i)
#pragma unroll
        for (int j = 0; j < 4; ++j) c1[i][j] = 0.0f;

    for (int kc = 0; kc < IN_F; kc += 32) {
        __syncthreads();
        float4 xa = make_float4(0.f, 0.f, 0.f, 0.f), xb = xa;
        int grow = row0 + lr;
        if (grow < N_NODES) {
            const float* xp = x + (size_t)grow * IN_F + kc + lq * 8;
            xa = *(const float4*)xp;
            xb = *(const float4*)(xp + 4);
        }
        int c0 = lq * 8;
        xs[(c0 + 0) * 68 + lr] = xa.x;
        xs[(c0 + 1) * 68 + lr] = xa.y;
        xs[(c0 + 2) * 68 + lr] = xa.z;
        xs[(c0 + 3) * 68 + lr] = xa.w;
        xs[(c0 + 4) * 68 + lr] = xb.x;
        xs[(c0 + 5) * 68 + lr] = xb.y;
        xs[(c0 + 6) * 68 + lr] = xb.z;
        xs[(c0 + 7) * 68 + lr] = xb.w;
        const float* wp = W1 + (size_t)(kc + wr) * HID + wq * 8;
        *(float4*)(ws + wr * 64 + wq * 8)     = *(const float4*)wp;
        *(float4*)(ws + wr * 64 + wq * 8 + 4) = *(const float4*)(wp + 4);
        __syncthreads();
#pragma unroll
        for (int k = 0; k < 32; ++k) {
            float4 a4 = *(const float4*)&xs[k * 68 + 4 * ry];
            float4 b4 = *(const float4*)&ws[k * 64 + 4 * cx];
            float av[4] = {a4.x, a4.y, a4.z, a4.w};
            float bv[4] = {b4.x, b4.y, b4.z, b4.w};
#pragma unroll
            for (int i = 0; i < 4; ++i)
#pragma unroll
                for (int j = 0; j < 4; ++j)
                    c1[i][j] = fmaf(av[i], bv[j], c1[i][j]);
        }
    }

    // ---- layer 2 ----
    __syncthreads();
#pragma unroll
    for (int i = 0; i < 4; ++i)
#pragma unroll
        for (int j = 0; j < 4; ++j)
            h1t[(4 * cx + j) * 68 + 4 * ry + i] = fmaxf(c1[i][j], 0.0f);
#pragma unroll
    for (int i = 0; i < 4; ++i) {
        int idx = tid + i * 256;
        ((float4*)ws2)[idx] = ((const float4*)W2)[idx];
    }
    __syncthreads();

    float c2[4][4];
#pragma unroll
    for (int i = 0; i < 4; ++i)
#pragma unroll
        for (int j = 0; j < 4; ++j) c2[i][j] = 0.0f;
#pragma unroll 4
    for (int k = 0; k < HID; ++k) {
        float4 a4 = *(const float4*)&h1t[k * 68 + 4 * ry];
        float4 b4 = *(const float4*)&ws2[k * 64 + 4 * cx];
        float av[4] = {a4.x, a4.y, a4.z, a4.w};
        float bv[4] = {b4.x, b4.y, b4.z, b4.w};
#pragma unroll
        for (int i = 0; i < 4; ++i)
#pragma unroll
            for (int j = 0; j < 4; ++j)
                c2[i][j] = fmaf(av[i], bv[j], c2[i][j]);
    }
#pragma unroll
    for (int i = 0; i < 4; ++i) {
        int row = row0 + 4 * ry + i;
        if (row < N_NODES) {
            ushort4 w;
            w.x = f2bf(fmaxf(c2[i][0], 0.0f));
            w.y = f2bf(fmaxf(c2[i][1], 0.0f));
            w.z = f2bf(fmaxf(c2[i][2], 0.0f));
            w.w = f2bf(fmaxf(c2[i][3], 0.0f));
            *(ushort4*)(h + (size_t)row * OUT_F + 4 * cx) = w;
        }
    }
}

// ---------------------------------------------------------------------------
// Initial combine: out = sigmoid(h . s) * h   (h is bf16)
__global__ void __launch_bounds__(256) combine_kernel(const unsigned short* __restrict__ feat,
                                                      const float* __restrict__ sv,
                                                      float* __restrict__ out) {
    int lane = threadIdx.x & 63;
    int node = blockIdx.x * 4 + (threadIdx.x >> 6);
    if (node >= N_NODES) return;
    float v = bf2f(feat[(size_t)node * OUT_F + lane]);
    float p = v * sv[lane];
#pragma unroll
    for (int off = 32; off >= 1; off >>= 1) p += __shfl_xor(p, off, 64);
    float score = 1.0f / (1.0f + expf(-p));
    out[(size_t)node * OUT_F + lane] = score * v;
}

// ---------------------------------------------------------------------------
// One hop + fused gate-combine. One wave per dst node; 8 edge-slots x 8
// feature-lanes; bf16 feat rows (128 B, one uint4/lane); f32 accumulation.
__global__ void __launch_bounds__(256) hop_combine_kernel(
        const unsigned short* __restrict__ feat,
        const int* __restrict__ row_start,
        const int2* __restrict__ csr,
        const float* __restrict__ sv,
        unsigned short* __restrict__ fnext,
        float* __restrict__ out) {
    int lane = threadIdx.x & 63;
    int node = blockIdx.x * 4 + (threadIdx.x >> 6);
    if (node >= N_NODES) return;
    int beg = row_start[node];
    int end = row_start[node + 1];
    int slot = lane >> 3;    // 0..7: edge slot
    int sub  = lane & 7;     // feature group: features 8*sub..8*sub+7

    float acc[8];
#pragma unroll
    for (int j = 0; j < 8; ++j) acc[j] = 0.0f;

    for (int i = beg + slot; i < end; i += 8) {
        int2 e = csr[i];                      // 8 lanes broadcast-load 8 B
        float nrm = __int_as_float(e.y);
        const unsigned short* fr = feat + (size_t)e.x * OUT_F + sub * 8;
        uint4 v = *(const uint4*)fr;          // 8 bf16 features
        acc[0] = fmaf(__uint_as_float(v.x << 16),          nrm, acc[0]);
        acc[1] = fmaf(__uint_as_float(v.x & 0xffff0000u),  nrm, acc[1]);
        acc[2] = fmaf(__uint_as_float(v.y << 16),          nrm, acc[2]);
        acc[3] = fmaf(__uint_as_float(v.y & 0xffff0000u),  nrm, acc[3]);
        acc[4] = fmaf(__uint_as_float(v.z << 16),          nrm, acc[4]);
        acc[5] = fmaf(__uint_as_float(v.z & 0xffff0000u),  nrm, acc[5]);
        acc[6] = fmaf(__uint_as_float(v.w << 16),          nrm, acc[6]);
        acc[7] = fmaf(__uint_as_float(v.w & 0xffff0000u),  nrm, acc[7]);
    }
#pragma unroll
    for (int off = 8; off <= 32; off <<= 1) {
#pragma unroll
        for (int j = 0; j < 8; ++j) acc[j] += __shfl_xor(acc[j], off, 64);
    }
    // gate: p = row . s
    float4 s0 = *(const float4*)(sv + sub * 8);
    float4 s1 = *(const float4*)(sv + sub * 8 + 4);
    float p = acc[0] * s0.x + acc[1] * s0.y + acc[2] * s0.z + acc[3] * s0.w
            + acc[4] * s1.x + acc[5] * s1.y + acc[6] * s1.z + acc[7] * s1.w;
#pragma unroll
    for (int off = 1; off <= 4; off <<= 1) p += __shfl_xor(p, off, 64);
    float score = 1.0f / (1.0f + expf(-p));

    if (slot == 0) {   // lanes 0..7 write the row
        uint4 w;
        w.x = (unsigned)f2bf(acc[0]) | ((unsigned)f2bf(acc[1]) << 16);
        w.y = (unsigned)f2bf(acc[2]) | ((unsigned)f2bf(acc[3]) << 16);
        w.z = (unsigned)f2bf(acc[4]) | ((unsigned)f2bf(acc[5]) << 16);
        w.w = (unsigned)f2bf(acc[6]) | ((unsigned)f2bf(acc[7]) << 16);
        *(uint4*)(fnext + (size_t)node * OUT_F + sub * 8) = w;
        float4* op = (float4*)(out + (size_t)node * OUT_F + sub * 8);
        float4 o0 = op[0], o1 = op[1];
        o0.x = fmaf(score, acc[0], o0.x);
        o0.y = fmaf(score, acc[1], o0.y);
        o0.z = fmaf(score, acc[2], o0.z);
        o0.w = fmaf(score, acc[3], o0.w);
        o1.x = fmaf(score, acc[4], o1.x);
        o1.y = fmaf(score, acc[5], o1.y);
        o1.z = fmaf(score, acc[6], o1.z);
        o1.w = fmaf(score, acc[7], o1.w);
        op[0] = o0;
        op[1] = o1;
    }
}

// ---------------------------------------------------------------------------
extern "C" void kernel_launch(void* const* d_in, const int* in_sizes, int n_in,
                              void* d_out, int out_size, void* d_ws, size_t ws_size,
                              hipStream_t stream) {
    const float* x  = (const float*)d_in[0];
    const void*  ei = d_in[1];
    const float* W1 = (const float*)d_in[2];
    const float* W2 = (const float*)d_in[3];
    const float* sv = (const float*)d_in[4];
    float* out = (float*)d_out;

    char* p = (char*)d_ws;
    auto alloc = [&](size_t bytes) -> char* {
        char* r = p;
        p += (bytes + 255) & ~(size_t)255;
        return r;
    };
    unsigned short* fA = (unsigned short*)alloc(sizeof(unsigned short) * N_NODES * OUT_F);
    unsigned short* fB = (unsigned short*)alloc(sizeof(unsigned short) * N_NODES * OUT_F);
    int*   src32     = (int*)alloc(sizeof(int) * N_EDGES);
    int*   dst32     = (int*)alloc(sizeof(int) * N_EDGES);
    int2*  csr       = (int2*)alloc(sizeof(int2) * N_EDGES);
    int*   deg_out   = (int*)alloc(sizeof(int) * N_NODES);
    int*   deg_in    = (int*)alloc(sizeof(int) * N_NODES);
    float* dinv_out  = (float*)alloc(sizeof(float) * N_NODES);
    float* dinv_in   = (float*)alloc(sizeof(float) * N_NODES);
    int*   row_start = (int*)alloc(sizeof(int) * (N_NODES + 1));
    int*   cursor    = (int*)alloc(sizeof(int) * N_NODES);
    int*   partial   = (int*)alloc(sizeof(int) * N_SCAN_BLOCKS);
    int*   flag      = (int*)alloc(256);

    hipMemsetAsync(deg_out, 0, sizeof(int) * N_NODES, stream);
    hipMemsetAsync(deg_in,  0, sizeof(int) * N_NODES, stream);
    hipMemsetAsync(flag,    0, sizeof(int), stream);

    detect_i32_kernel<<<4, 256, 0, stream>>>((const unsigned int*)ei, flag);
    edges_deg_kernel<<<(N_EDGES + 255) / 256, 256, 0, stream>>>(ei, flag, src32, dst32,
                                                                deg_out, deg_in);
    dinv_kernel<<<(N_NODES + 255) / 256, 256, 0, stream>>>(deg_out, deg_in,
                                                           dinv_out, dinv_in);
    block_sum_kernel<<<N_SCAN_BLOCKS, 256, 0, stream>>>(deg_in, partial);
    scan_partial_kernel<<<1, 64, 0, stream>>>(partial, row_start);
    row_start_kernel<<<N_SCAN_BLOCKS, 256, 0, stream>>>(deg_in, partial, row_start, cursor);
    scatter_kernel<<<(N_EDGES + 255) / 256, 256, 0, stream>>>(src32, dst32, dinv_out, dinv_in,
                                                              cursor, csr);

    int mlp_blocks = (N_NODES + 63) / 64;                   // 1563
    mlp_kernel<<<mlp_blocks, 256, 0, stream>>>(x, W1, W2, fA);

    int node_blocks = (N_NODES + 3) / 4;                    // 25000
    combine_kernel<<<node_blocks, 256, 0, stream>>>(fA, sv, out);

    unsigned short* cur = fA;
    unsigned short* nxt = fB;
    for (int hop = 0; hop < K_HOPS; ++hop) {
        hop_combine_kernel<<<node_blocks, 256, 0, stream>>>(cur, row_start, csr,
                                                            sv, nxt, out);
        unsigned short* t = cur; cur = nxt; nxt = t;
    }
}

// Round 4
// 1091.330 us; speedup vs baseline: 7.1318x; 1.1582x over previous
//
#include <hip/hip_runtime.h>
#include <hip/hip_bf16.h>

#define N_NODES 100000
#define N_EDGES 3200000
#define IN_F 512
#define HID 64
#define OUT_F 64
#define K_HOPS 10
#define N_SCAN_BLOCKS ((N_NODES + 255) / 256)   // 391

// histogram geometry: 4 ranges of 32768 bins cover 131072 >= N_NODES
#define HIST_BLOCKS 64
#define HIST_BINS 32768
#define HIST_WORDS (HIST_BINS / 2)              // packed dual-uint16
#define EDGES_PER_HIST_BLOCK (N_EDGES / HIST_BLOCKS)  // 50000

static __device__ __forceinline__ unsigned short f2bf(float f) {
    unsigned int u = __float_as_uint(f);
    u += 0x7FFFu + ((u >> 16) & 1u);            // round-to-nearest-even
    return (unsigned short)(u >> 16);
}
static __device__ __forceinline__ float bf2f(unsigned short s) {
    return __uint_as_float(((unsigned int)s) << 16);
}

// ---------------------------------------------------------------------------
// Detect edge_index storage: int64 (high 32-bit words all zero) vs int32.
__global__ void detect_i32_kernel(const unsigned int* ei_words, int* flag_is32) {
    int i = blockIdx.x * blockDim.x + threadIdx.x;  // 0..1023
    unsigned int w = ei_words[2 * i + 1];
    if (w != 0u) atomicOr(flag_is32, 1);
}

// Pure streaming conversion, no atomics. 2 edges per thread.
__global__ void __launch_bounds__(256) convert_kernel(const void* ei_raw, const int* flag_is32,
                                                      int* __restrict__ src32,
                                                      int* __restrict__ dst32) {
    int t = blockIdx.x * blockDim.x + threadIdx.x;     // 0 .. N_EDGES/2-1
    if (t >= N_EDGES / 2) return;
    if (*flag_is32) {
        const int2* ei = (const int2*)ei_raw;
        *(int2*)(src32 + 2 * t) = ei[t];
        *(int2*)(dst32 + 2 * t) = ei[N_EDGES / 2 + t];
    } else {
        const longlong2* ei = (const longlong2*)ei_raw;
        longlong2 s = ei[t];
        longlong2 d = ei[N_EDGES / 2 + t];
        *(int2*)(src32 + 2 * t) = make_int2((int)s.x, (int)s.y);
        *(int2*)(dst32 + 2 * t) = make_int2((int)d.x, (int)d.y);
    }
}

// Partial histograms in LDS (packed dual-uint16), no global atomics.
// grid.x = HIST_BLOCKS edge slices, grid.y = 8: (arr = y>>2) x (range = y&3).
__global__ void __launch_bounds__(256) hist_kernel(const int* __restrict__ src32,
                                                   const int* __restrict__ dst32,
                                                   unsigned int* __restrict__ partials) {
    __shared__ unsigned int cnt[HIST_WORDS];   // 64 KB
    int tid = threadIdx.x;
#pragma unroll
    for (int w = tid; w < HIST_WORDS; w += 256) cnt[w] = 0u;
    __syncthreads();

    int arr = blockIdx.y >> 2;
    int range = blockIdx.y & 3;
    unsigned lo = (unsigned)(range * HIST_BINS);
    const int* a = arr ? dst32 : src32;
    int beg = blockIdx.x * EDGES_PER_HIST_BLOCK;
    int end = beg + EDGES_PER_HIST_BLOCK;
    for (int i = beg + tid; i < end; i += 256) {
        unsigned v = (unsigned)a[i] - lo;
        if (v < HIST_BINS) atomicAdd(&cnt[v >> 1], 1u << ((v & 1u) * 16u));
    }
    __syncthreads();

    unsigned int* outp = partials + ((size_t)(blockIdx.y * HIST_BLOCKS + blockIdx.x)) * HIST_WORDS;
#pragma unroll
    for (int w = tid; w < HIST_WORDS / 4; w += 256)
        ((uint4*)outp)[w] = ((const uint4*)cnt)[w];
}

// Sum partials per bin; fuse dinv computation. grid.x covers nodes, grid.y = arr.
__global__ void __launch_bounds__(256) hist_reduce_kernel(const unsigned int* __restrict__ partials,
                                                          int* __restrict__ deg_in,
                                                          float* __restrict__ dinv_out,
                                                          float* __restrict__ dinv_in) {
    int i = blockIdx.x * blockDim.x + threadIdx.x;
    if (i >= N_NODES) return;
    int arr = blockIdx.y;
    int range = i >> 15;
    int off = i & (HIST_BINS - 1);
    int word = off >> 1;
    int sh = (off & 1) * 16;
    const unsigned int* base = partials + ((size_t)(arr * 4 + range) * HIST_BLOCKS) * HIST_WORDS + word;
    unsigned total = 0;
#pragma unroll 8
    for (int b = 0; b < HIST_BLOCKS; ++b)
        total += (base[(size_t)b * HIST_WORDS] >> sh) & 0xffffu;
    float dv = (total > 0) ? rsqrtf((float)total) : 0.0f;
    if (arr == 0) {
        dinv_out[i] = dv;
    } else {
        deg_in[i] = (int)total;
        dinv_in[i] = dv;
    }
}

// --------------------------- CSR build (scan + scatter) ---------------------
__global__ void block_sum_kernel(const int* __restrict__ deg, int* __restrict__ partial) {
    __shared__ int s[256];
    int t = threadIdx.x;
    int i = blockIdx.x * 256 + t;
    s[t] = (i < N_NODES) ? deg[i] : 0;
    __syncthreads();
    for (int off = 128; off >= 1; off >>= 1) {
        if (t < off) s[t] += s[t + off];
        __syncthreads();
    }
    if (t == 0) partial[blockIdx.x] = s[0];
}

__global__ void scan_partial_kernel(int* partial, int* row_start) {
    if (threadIdx.x == 0 && blockIdx.x == 0) {
        int acc = 0;
        for (int b = 0; b < N_SCAN_BLOCKS; ++b) {
            int v = partial[b];
            partial[b] = acc;
            acc += v;
        }
        row_start[N_NODES] = acc;
    }
}

__global__ void row_start_kernel(const int* __restrict__ deg, const int* __restrict__ partial,
                                 int* __restrict__ row_start, int* __restrict__ cursor) {
    __shared__ int s[256];
    int t = threadIdx.x;
    int i = blockIdx.x * 256 + t;
    int v = (i < N_NODES) ? deg[i] : 0;
    s[t] = v;
    __syncthreads();
    for (int off = 1; off < 256; off <<= 1) {
        int add = (t >= off) ? s[t - off] : 0;
        __syncthreads();
        s[t] += add;
        __syncthreads();
    }
    if (i < N_NODES) {
        int excl = s[t] - v + partial[blockIdx.x];
        row_start[i] = excl;
        cursor[i] = excl;
    }
}

__global__ void scatter_kernel(const int* __restrict__ src32, const int* __restrict__ dst32,
                               const float* __restrict__ dinv_out, const float* __restrict__ dinv_in,
                               int* __restrict__ cursor, int2* __restrict__ csr) {
    int e = blockIdx.x * blockDim.x + threadIdx.x;
    if (e >= N_EDGES) return;
    int s = src32[e], d = dst32[e];
    float nrm = dinv_out[s] * dinv_in[d];
    int pos = atomicAdd(&cursor[d], 1);
    csr[pos] = make_int2(s, __float_as_int(nrm));
}

// ---------------------------------------------------------------------------
// Fused 2-layer MLP: h = relu(relu(x@W1)@W2), output bf16.
__global__ void __launch_bounds__(256) mlp_kernel(const float* __restrict__ x,
                                                  const float* __restrict__ W1,
                                                  const float* __restrict__ W2,
                                                  unsigned short* __restrict__ h) {
    __shared__ float smem[64 * 68 + 64 * 64];   // 33.8 KB
    float* xs  = smem;                           // [32][68]
    float* ws  = smem + 32 * 68;                 // [32][64]
    float* h1t = smem;                           // [64][68]
    float* ws2 = smem + 64 * 68;                 // [64][64]

    int tid = threadIdx.x;
    int cx = tid & 15;
    int ry = tid >> 4;
    int row0 = blockIdx.x * 64;

    int lr = tid >> 2;
    int lq = tid & 3;
    int wr = tid >> 3;
    int wq = tid & 7;

    float c1[4][4];
#pragma unroll
    for (int i = 0; i < 4; ++i)
#pragma unroll
        for (int j = 0; j < 4; ++j) c1[i][j] = 0.0f;

    for (int kc = 0; kc < IN_F; kc += 32) {
        __syncthreads();
        float4 xa = make_float4(0.f, 0.f, 0.f, 0.f), xb = xa;
        int grow = row0 + lr;
        if (grow < N_NODES) {
            const float* xp = x + (size_t)grow * IN_F + kc + lq * 8;
            xa = *(const float4*)xp;
            xb = *(const float4*)(xp + 4);
        }
        int c0 = lq * 8;
        xs[(c0 + 0) * 68 + lr] = xa.x;
        xs[(c0 + 1) * 68 + lr] = xa.y;
        xs[(c0 + 2) * 68 + lr] = xa.z;
        xs[(c0 + 3) * 68 + lr] = xa.w;
        xs[(c0 + 4) * 68 + lr] = xb.x;
        xs[(c0 + 5) * 68 + lr] = xb.y;
        xs[(c0 + 6) * 68 + lr] = xb.z;
        xs[(c0 + 7) * 68 + lr] = xb.w;
        const float* wp = W1 + (size_t)(kc + wr) * HID + wq * 8;
        *(float4*)(ws + wr * 64 + wq * 8)     = *(const float4*)wp;
        *(float4*)(ws + wr * 64 + wq * 8 + 4) = *(const float4*)(wp + 4);
        __syncthreads();
#pragma unroll
        for (int k = 0; k < 32; ++k) {
            float4 a4 = *(const float4*)&xs[k * 68 + 4 * ry];
            float4 b4 = *(const float4*)&ws[k * 64 + 4 * cx];
            float av[4] = {a4.x, a4.y, a4.z, a4.w};
            float bv[4] = {b4.x, b4.y, b4.z, b4.w};
#pragma unroll
            for (int i = 0; i < 4; ++i)
#pragma unroll
                for (int j = 0; j < 4; ++j)
                    c1[i][j] = fmaf(av[i], bv[j], c1[i][j]);
        }
    }

    __syncthreads();
#pragma unroll
    for (int i = 0; i < 4; ++i)
#pragma unroll
        for (int j = 0; j < 4; ++j)
            h1t[(4 * cx + j) * 68 + 4 * ry + i] = fmaxf(c1[i][j], 0.0f);
#pragma unroll
    for (int i = 0; i < 4; ++i) {
        int idx = tid + i * 256;
        ((float4*)ws2)[idx] = ((const float4*)W2)[idx];
    }
    __syncthreads();

    float c2[4][4];
#pragma unroll
    for (int i = 0; i < 4; ++i)
#pragma unroll
        for (int j = 0; j < 4; ++j) c2[i][j] = 0.0f;
#pragma unroll 4
    for (int k = 0; k < HID; ++k) {
        float4 a4 = *(const float4*)&h1t[k * 68 + 4 * ry];
        float4 b4 = *(const float4*)&ws2[k * 64 + 4 * cx];
        float av[4] = {a4.x, a4.y, a4.z, a4.w};
        float bv[4] = {b4.x, b4.y, b4.z, b4.w};
#pragma unroll
        for (int i = 0; i < 4; ++i)
#pragma unroll
            for (int j = 0; j < 4; ++j)
                c2[i][j] = fmaf(av[i], bv[j], c2[i][j]);
    }
#pragma unroll
    for (int i = 0; i < 4; ++i) {
        int row = row0 + 4 * ry + i;
        if (row < N_NODES) {
            ushort4 w;
            w.x = f2bf(fmaxf(c2[i][0], 0.0f));
            w.y = f2bf(fmaxf(c2[i][1], 0.0f));
            w.z = f2bf(fmaxf(c2[i][2], 0.0f));
            w.w = f2bf(fmaxf(c2[i][3], 0.0f));
            *(ushort4*)(h + (size_t)row * OUT_F + 4 * cx) = w;
        }
    }
}

// ---------------------------------------------------------------------------
// Initial combine: out = sigmoid(h . s) * h   (h is bf16)
__global__ void __launch_bounds__(256) combine_kernel(const unsigned short* __restrict__ feat,
                                                      const float* __restrict__ sv,
                                                      float* __restrict__ out) {
    int lane = threadIdx.x & 63;
    int node = blockIdx.x * 4 + (threadIdx.x >> 6);
    if (node >= N_NODES) return;
    float v = bf2f(feat[(size_t)node * OUT_F + lane]);
    float p = v * sv[lane];
#pragma unroll
    for (int off = 32; off >= 1; off >>= 1) p += __shfl_xor(p, off, 64);
    float score = 1.0f / (1.0f + expf(-p));
    out[(size_t)node * OUT_F + lane] = score * v;
}

// ---------------------------------------------------------------------------
// One hop + fused gate-combine. One wave per dst node; 8 edge-slots x 8
// feature-lanes; bf16 feat rows (128 B, one uint4/lane); f32 accumulation.
__global__ void __launch_bounds__(256) hop_combine_kernel(
        const unsigned short* __restrict__ feat,
        const int* __restrict__ row_start,
        const int2* __restrict__ csr,
        const float* __restrict__ sv,
        unsigned short* __restrict__ fnext,
        float* __restrict__ out) {
    int lane = threadIdx.x & 63;
    int node = blockIdx.x * 4 + (threadIdx.x >> 6);
    if (node >= N_NODES) return;
    int beg = row_start[node];
    int end = row_start[node + 1];
    int slot = lane >> 3;    // 0..7: edge slot
    int sub  = lane & 7;     // feature group: features 8*sub..8*sub+7

    float acc[8];
#pragma unroll
    for (int j = 0; j < 8; ++j) acc[j] = 0.0f;

    for (int i = beg + slot; i < end; i += 8) {
        int2 e = csr[i];
        float nrm = __int_as_float(e.y);
        const unsigned short* fr = feat + (size_t)e.x * OUT_F + sub * 8;
        uint4 v = *(const uint4*)fr;
        acc[0] = fmaf(__uint_as_float(v.x << 16),          nrm, acc[0]);
        acc[1] = fmaf(__uint_as_float(v.x & 0xffff0000u),  nrm, acc[1]);
        acc[2] = fmaf(__uint_as_float(v.y << 16),          nrm, acc[2]);
        acc[3] = fmaf(__uint_as_float(v.y & 0xffff0000u),  nrm, acc[3]);
        acc[4] = fmaf(__uint_as_float(v.z << 16),          nrm, acc[4]);
        acc[5] = fmaf(__uint_as_float(v.z & 0xffff0000u),  nrm, acc[5]);
        acc[6] = fmaf(__uint_as_float(v.w << 16),          nrm, acc[6]);
        acc[7] = fmaf(__uint_as_float(v.w & 0xffff0000u),  nrm, acc[7]);
    }
#pragma unroll
    for (int off = 8; off <= 32; off <<= 1) {
#pragma unroll
        for (int j = 0; j < 8; ++j) acc[j] += __shfl_xor(acc[j], off, 64);
    }
    float4 s0 = *(const float4*)(sv + sub * 8);
    float4 s1 = *(const float4*)(sv + sub * 8 + 4);
    float p = acc[0] * s0.x + acc[1] * s0.y + acc[2] * s0.z + acc[3] * s0.w
            + acc[4] * s1.x + acc[5] * s1.y + acc[6] * s1.z + acc[7] * s1.w;
#pragma unroll
    for (int off = 1; off <= 4; off <<= 1) p += __shfl_xor(p, off, 64);
    float score = 1.0f / (1.0f + expf(-p));

    if (slot == 0) {
        uint4 w;
        w.x = (unsigned)f2bf(acc[0]) | ((unsigned)f2bf(acc[1]) << 16);
        w.y = (unsigned)f2bf(acc[2]) | ((unsigned)f2bf(acc[3]) << 16);
        w.z = (unsigned)f2bf(acc[4]) | ((unsigned)f2bf(acc[5]) << 16);
        w.w = (unsigned)f2bf(acc[6]) | ((unsigned)f2bf(acc[7]) << 16);
        *(uint4*)(fnext + (size_t)node * OUT_F + sub * 8) = w;
        float4* op = (float4*)(out + (size_t)node * OUT_F + sub * 8);
        float4 o0 = op[0], o1 = op[1];
        o0.x = fmaf(score, acc[0], o0.x);
        o0.y = fmaf(score, acc[1], o0.y);
        o0.z = fmaf(score, acc[2], o0.z);
        o0.w = fmaf(score, acc[3], o0.w);
        o1.x = fmaf(score, acc[4], o1.x);
        o1.y = fmaf(score, acc[5], o1.y);
        o1.z = fmaf(score, acc[6], o1.z);
        o1.w = fmaf(score, acc[7], o1.w);
        op[0] = o0;
        op[1] = o1;
    }
}

// ---------------------------------------------------------------------------
extern "C" void kernel_launch(void* const* d_in, const int* in_sizes, int n_in,
                              void* d_out, int out_size, void* d_ws, size_t ws_size,
                              hipStream_t stream) {
    const float* x  = (const float*)d_in[0];
    const void*  ei = d_in[1];
    const float* W1 = (const float*)d_in[2];
    const float* W2 = (const float*)d_in[3];
    const float* sv = (const float*)d_in[4];
    float* out = (float*)d_out;

    char* p = (char*)d_ws;
    auto alloc = [&](size_t bytes) -> char* {
        char* r = p;
        p += (bytes + 255) & ~(size_t)255;
        return r;
    };
    unsigned short* fA = (unsigned short*)alloc(sizeof(unsigned short) * N_NODES * OUT_F);
    unsigned short* fB = (unsigned short*)alloc(sizeof(unsigned short) * N_NODES * OUT_F);
    int*   src32     = (int*)alloc(sizeof(int) * N_EDGES);
    int*   dst32     = (int*)alloc(sizeof(int) * N_EDGES);
    // partials (33.55 MB) and csr (25.6 MB) are never alive simultaneously: alias.
    size_t partials_bytes = sizeof(unsigned int) * 8 * HIST_BLOCKS * HIST_WORDS;
    char*  shared_region = alloc(partials_bytes);
    unsigned int* partials = (unsigned int*)shared_region;
    int2*  csr       = (int2*)shared_region;
    int*   deg_in    = (int*)alloc(sizeof(int) * N_NODES);
    float* dinv_out  = (float*)alloc(sizeof(float) * N_NODES);
    float* dinv_in   = (float*)alloc(sizeof(float) * N_NODES);
    int*   row_start = (int*)alloc(sizeof(int) * (N_NODES + 1));
    int*   cursor    = (int*)alloc(sizeof(int) * N_NODES);
    int*   partial   = (int*)alloc(sizeof(int) * N_SCAN_BLOCKS);
    int*   flag      = (int*)alloc(256);

    hipMemsetAsync(flag, 0, sizeof(int), stream);

    detect_i32_kernel<<<4, 256, 0, stream>>>((const unsigned int*)ei, flag);
    convert_kernel<<<(N_EDGES / 2 + 255) / 256, 256, 0, stream>>>(ei, flag, src32, dst32);
    hist_kernel<<<dim3(HIST_BLOCKS, 8), 256, 0, stream>>>(src32, dst32, partials);
    hist_reduce_kernel<<<dim3((N_NODES + 255) / 256, 2), 256, 0, stream>>>(partials, deg_in,
                                                                           dinv_out, dinv_in);
    block_sum_kernel<<<N_SCAN_BLOCKS, 256, 0, stream>>>(deg_in, partial);
    scan_partial_kernel<<<1, 64, 0, stream>>>(partial, row_start);
    row_start_kernel<<<N_SCAN_BLOCKS, 256, 0, stream>>>(deg_in, partial, row_start, cursor);
    scatter_kernel<<<(N_EDGES + 255) / 256, 256, 0, stream>>>(src32, dst32, dinv_out, dinv_in,
                                                              cursor, csr);

    int mlp_blocks = (N_NODES + 63) / 64;                   // 1563
    mlp_kernel<<<mlp_blocks, 256, 0, stream>>>(x, W1, W2, fA);

    int node_blocks = (N_NODES + 3) / 4;                    // 25000
    combine_kernel<<<node_blocks, 256, 0, stream>>>(fA, sv, out);

    unsigned short* cur = fA;
    unsigned short* nxt = fB;
    for (int hop = 0; hop < K_HOPS; ++hop) {
        hop_combine_kernel<<<node_blocks, 256, 0, stream>>>(cur, row_start, csr,
                                                            sv, nxt, out);
        unsigned short* t = cur; cur = nxt; nxt = t;
    }
}